// Round 9
// baseline (113.296 us; speedup 1.0000x reference)
//
#include <hip/hip_runtime.h>
#include <hip/hip_bf16.h>
#include <math.h>

// Problem constants
#define BB 64
#define QQ 100
#define NN 16
#define CC 2048            // NUM_CLASSES + 1
#define TIME_WEIGHT 2.0f
#define EOS_COEF 0.1f

__device__ __forceinline__ float readlane_f(float x, int lane) {
    return __int_as_float(__builtin_amdgcn_readlane(__float_as_int(x), lane));
}

// ---------------------------------------------------------------------------
// Kernel 1: 800 blocks x 256 threads; each wave handles TWO (b,q) rows
// (16 outstanding dwordx4 loads/lane for HBM BW):
//   logZ[b,q] = logsumexp(logits[b,q,:])
//   CgT[b][q][n] = -softmax[label_n] + 2*|pt - ts_n|  (coalesced 64B bursts;
//     lanes 0..15 handle row A, lanes 16..31 row B)
//   lsepart[block] = sum over 8 rows of (logZ - logit[class 0])
// Block 0 additionally zero-inits the atomic accumulators for kernel 2.
// ---------------------------------------------------------------------------
__global__ __launch_bounds__(256) void lse_cost_kernel(
    const float* __restrict__ logits, const float* __restrict__ ptime,
    const int* __restrict__ labels, const float* __restrict__ tstamp,
    float* __restrict__ logZ, float* __restrict__ CgT,
    float* __restrict__ lsepart, float* __restrict__ sums, int* __restrict__ counter)
{
    if (blockIdx.x == 0 && threadIdx.x == 0) {
        sums[0] = 0.f; sums[1] = 0.f; *counter = 0;
    }
    const int wave = threadIdx.x >> 6;
    const int lane = threadIdx.x & 63;
    const int bqA = blockIdx.x * 8 + wave * 2;     // rows bqA and bqA+1 (< 6400)
    const int bqB = bqA + 1;
    const float4* rowA = (const float4*)(logits + (size_t)bqA * CC);
    const float4* rowB = (const float4*)(logits + (size_t)bqB * CC);

    float4 va[8], vb[8];
    #pragma unroll
    for (int c = 0; c < 8; ++c) { va[c] = rowA[c * 64 + lane]; vb[c] = rowB[c * 64 + lane]; }

    float ma = -INFINITY, mb = -INFINITY;
    #pragma unroll
    for (int c = 0; c < 8; ++c) {
        ma = fmaxf(ma, fmaxf(fmaxf(va[c].x, va[c].y), fmaxf(va[c].z, va[c].w)));
        mb = fmaxf(mb, fmaxf(fmaxf(vb[c].x, vb[c].y), fmaxf(vb[c].z, vb[c].w)));
    }
    #pragma unroll
    for (int s = 1; s < 64; s <<= 1) {
        ma = fmaxf(ma, __shfl_xor(ma, s, 64));
        mb = fmaxf(mb, __shfl_xor(mb, s, 64));
    }

    float sa = 0.f, sb = 0.f;
    #pragma unroll
    for (int c = 0; c < 8; ++c) {
        sa += expf(va[c].x - ma) + expf(va[c].y - ma) +
              expf(va[c].z - ma) + expf(va[c].w - ma);
        sb += expf(vb[c].x - mb) + expf(vb[c].y - mb) +
              expf(vb[c].z - mb) + expf(vb[c].w - mb);
    }
    #pragma unroll
    for (int s = 1; s < 64; s <<= 1) {
        sa += __shfl_xor(sa, s, 64);
        sb += __shfl_xor(sb, s, 64);
    }

    const float lzA = ma + logf(sa);
    const float lzB = mb + logf(sb);
    if (lane == 0) { logZ[bqA] = lzA; logZ[bqB] = lzB; }

    // cost entries: lanes 0..15 -> row A targets, lanes 16..31 -> row B
    if (lane < 32) {
        const int n = lane & 15;
        const int bq = (lane < 16) ? bqA : bqB;
        const float lz = (lane < 16) ? lzA : lzB;
        const int b = bq / QQ;
        int lab = labels[b * NN + n];
        float ts = tstamp[b * NN + n];
        float pt = ptime[bq];
        float lg = logits[(size_t)bq * CC + lab];     // L1-hot gather (same row)
        float cc = -expf(lg - lz);
        float ct = fabsf(pt - ts);
        float val = cc + TIME_WEIGHT * ct;
        if (isnan(val)) val = 100.0f;
        else if (isinf(val)) val = (val > 0.f) ? 100.0f : -100.0f;
        CgT[(size_t)bq * NN + n] = val;
    }

    // EOS nll partials: logit[class 0] is va[0].x / vb[0].x on lane 0
    __shared__ float red[8];
    if (lane == 0) {
        red[wave * 2]     = lzA - va[0].x;
        red[wave * 2 + 1] = lzB - vb[0].x;
    }
    __syncthreads();
    if (threadIdx.x == 0) {
        float r = 0.f;
        #pragma unroll
        for (int k = 0; k < 8; ++k) r += red[k];
        lsepart[blockIdx.x] = r;
    }
}

// ---------------------------------------------------------------------------
// Kernel 2: Jonker-Volgenant assignment, one wave per batch, all-float
// solver (reference promotes f32 costs to f64; f32 here may flip near-tie
// assignments only, which perturbs the scalar loss by <<1e-1 threshold).
// Cost matrix register-resident (two owned columns as 8 float4s, selected
// by a cndmask tree on the uniform row index -> no scratch, no LDS).
// Min-reduction: two-phase 8-way gather (8 single-bpermute shuffles + fmin
// tree; 8 readlanes + fmin tree). Winner via equality ballots, cols 1..64
// prioritized over 65..100 (argmin lowest-index tie-break; fmin returns a
// bit-exact member of the candidate set).
// Fused tail: CE correction + L1 time partials -> device atomics; last of
// the 64 blocks folds lsepart and writes the final scalar loss.
// ---------------------------------------------------------------------------
__global__ __launch_bounds__(64) void hungarian_kernel(
    const float* __restrict__ CgT, const float* __restrict__ logits,
    const float* __restrict__ ptime, const int* __restrict__ labels,
    const float* __restrict__ tstamp, const float* __restrict__ logZ,
    const float* __restrict__ lsepart, float* __restrict__ sums,
    int* __restrict__ counter, float* __restrict__ out)
{
    const int b = blockIdx.x;
    const int t = threadIdx.x;

    __shared__ int qsl[NN];

    // Lane t owns columns jc0 = t+1 and (if <=100) jc1 = t+65 (1-based).
    const int jc0 = t + 1;
    const int jc1 = t + 65;
    const bool has2 = (jc1 <= QQ);
    const int t2 = has2 ? (t + 64) : t;            // clamp keeps loads in-bounds

    // owned cost columns in registers (16 floats each, as 4 float4s)
    const float* colbase = CgT + (size_t)b * QQ * NN;
    const float4* cp0 = (const float4*)(colbase + t * NN);
    const float4* cp1 = (const float4*)(colbase + t2 * NN);
    const float4 a0 = cp0[0], a1 = cp0[1], a2 = cp0[2], a3 = cp0[3];
    const float4 b0 = cp1[0], b1 = cp1[1], b2 = cp1[2], b3 = cp1[3];

    float v0 = 0.f, v1 = 0.f;           // column potentials (owned)
    float ureg = 0.f;                   // lane r holds u[r+1] (lanes 0..15)
    int preg0 = 0, preg1 = 0;           // p[jc0], p[jc1] (0 = free)
    const float INF = __builtin_inff();
    const int gbase = (t & 7) << 3;     // base lane of my gather chunk

    for (int i = 1; i <= NN; ++i) {
        float minv0 = INF, minv1 = INF;
        bool used0 = false, used1 = false;
        int way0 = 0, way1 = 0;
        bool inTree = (t == i - 1);     // p[0] = i enters the tree at start
        int j0 = 0;
        int i0 = i;                      // p[0]

        while (true) {
            used0 |= (j0 == jc0);
            used1 |= (j0 == jc1);
            inTree = inTree || (t == i0 - 1);
            const float u_i0 = readlane_f(ureg, i0 - 1);

            // register select of row (i0-1)'s two cost entries: cndmask tree
            const int mrow = i0 - 1;     // wave-uniform, 0..15
            float4 ha = (mrow & 8) ? ((mrow & 4) ? a3 : a2)
                                   : ((mrow & 4) ? a1 : a0);
            float4 hb = (mrow & 8) ? ((mrow & 4) ? b3 : b2)
                                   : ((mrow & 4) ? b1 : b0);
            float ca = (mrow & 2) ? ((mrow & 1) ? ha.w : ha.z)
                                  : ((mrow & 1) ? ha.y : ha.x);
            float cb = (mrow & 2) ? ((mrow & 1) ? hb.w : hb.z)
                                  : ((mrow & 1) ? hb.y : hb.x);

            if (!used0) {
                float cur = ca - u_i0 - v0;
                if (cur < minv0) { minv0 = cur; way0 = j0; }
            }
            if (has2 && !used1) {
                float cur = cb - u_i0 - v1;
                if (cur < minv1) { minv1 = cur; way1 = j0; }
            }

            // ---- two-phase 8-way-gather min reduction (f32) ----
            float m0 = used0 ? INF : minv0;
            float m1 = (has2 && !used1) ? minv1 : INF;
            float mm = fminf(m0, m1);

            float g0 = __shfl(mm, gbase + 0, 64);
            float g1 = __shfl(mm, gbase + 1, 64);
            float g2 = __shfl(mm, gbase + 2, 64);
            float g3 = __shfl(mm, gbase + 3, 64);
            float g4 = __shfl(mm, gbase + 4, 64);
            float g5 = __shfl(mm, gbase + 5, 64);
            float g6 = __shfl(mm, gbase + 6, 64);
            float g7 = __shfl(mm, gbase + 7, 64);
            float cmin = fminf(fminf(fminf(g0, g1), fminf(g2, g3)),
                               fminf(fminf(g4, g5), fminf(g6, g7)));
            // chunk-min of chunk c now lives in lanes {c, c+8, ...}
            float h0 = readlane_f(cmin, 0);
            float h1 = readlane_f(cmin, 1);
            float h2 = readlane_f(cmin, 2);
            float h3 = readlane_f(cmin, 3);
            float h4 = readlane_f(cmin, 4);
            float h5 = readlane_f(cmin, 5);
            float h6 = readlane_f(cmin, 6);
            float h7 = readlane_f(cmin, 7);
            float gmin = fminf(fminf(fminf(h0, h1), fminf(h2, h3)),
                               fminf(fminf(h4, h5), fminf(h6, h7)));

            // winning column: ballot A (cols 1..64) has priority, then B
            unsigned long long A  = __ballot(!used0 && (minv0 == gmin));
            unsigned long long Bm = __ballot(has2 && !used1 && (minv1 == gmin));
            int j1 = (A != 0ull) ? ((int)__builtin_ctzll(A) + 1)
                                 : ((int)__builtin_ctzll(Bm) + 65);
            const float delta = gmin;

            if (inTree) ureg += delta;                   // u[p[used]] += delta
            if (used0) v0 -= delta; else minv0 -= delta;
            if (has2) { if (used1) v1 -= delta; else minv1 -= delta; }

            j0 = j1;
            int pj = (j0 <= 64) ? __builtin_amdgcn_readlane(preg0, j0 - 1)
                                : __builtin_amdgcn_readlane(preg1, j0 - 65);
            if (pj == 0) break;
            i0 = pj;
        }

        // augment along the alternating path (uniform walk)
        while (j0 != 0) {
            int jn = (j0 <= 64) ? __builtin_amdgcn_readlane(way0, j0 - 1)
                                : __builtin_amdgcn_readlane(way1, j0 - 65);
            int pv;
            if (jn == 0) pv = i;
            else pv = (jn <= 64) ? __builtin_amdgcn_readlane(preg0, jn - 1)
                                 : __builtin_amdgcn_readlane(preg1, jn - 65);
            if (j0 == jc0) preg0 = pv;
            if (has2 && j0 == jc1) preg1 = pv;
            j0 = jn;
        }
    }

    // extract matches: qsl[target row] = column
    if (preg0 > 0) qsl[preg0 - 1] = jc0 - 1;
    if (has2 && preg1 > 0) qsl[preg1 - 1] = jc1 - 1;
    __syncthreads();

    // fused tail: CE correction + time-loss partials for this batch
    float corr = 0.f, tl = 0.f;
    if (t < NN) {
        int qcol = qsl[t];
        int lab = labels[b * NN + t];
        int bq = b * QQ + qcol;
        float lz = logZ[bq];
        float lgm = logits[(size_t)bq * CC + lab];
        float lg0 = logits[(size_t)bq * CC];
        corr = (lz - lgm) - EOS_COEF * (lz - lg0);
        tl = fabsf(ptime[bq] - tstamp[b * NN + t]);
    }
    #pragma unroll
    for (int s = 1; s < 64; s <<= 1) {
        corr += __shfl_xor(corr, s, 64);
        tl   += __shfl_xor(tl, s, 64);
    }

    int old = 0;
    if (t == 0) {
        atomicAdd(&sums[0], corr);
        atomicAdd(&sums[1], tl);
        __threadfence();                 // release partials before counter bump
        old = atomicAdd(counter, 1);
    }
    old = __shfl(old, 0, 64);
    if (old == BB - 1) {                 // last block finalizes
        __threadfence();                 // acquire others' partials
        float r0 = 0.f;
        #pragma unroll
        for (int k = 0; k < 13; ++k) {
            int idx = t + 64 * k;
            if (idx < 800) r0 += lsepart[idx];           // 800 = 64*12.5
        }
        #pragma unroll
        for (int s = 1; s < 64; s <<= 1) r0 += __shfl_xor(r0, s, 64);
        if (t == 0) {
            float s0 = atomicAdd(&sums[0], 0.0f);
            float s1 = atomicAdd(&sums[1], 0.0f);
            const float sum_w = (float)(BB * NN) * 1.0f
                              + (float)(BB * (QQ - NN)) * EOS_COEF;   // 1561.6
            float loss_ce = (EOS_COEF * r0 + s0) / sum_w;
            float loss_t  = s1 / (float)(BB * NN);
            out[0] = loss_ce + TIME_WEIGHT * loss_t;
        }
    }
}

// ---------------------------------------------------------------------------
// Workspace layout (bytes):
//   [0,      25600)  : float logZ[6400]
//   [25600, 435200)  : float CgT[64*100*16]   (transposed cost matrix)
//   [435200, 438400) : float lsepart[800]
//   [438400, 438408) : float sums[2]   {ce_corr, time}   (zeroed by kernel 1)
//   [438408, 438412) : int   counter                     (zeroed by kernel 1)
// ---------------------------------------------------------------------------
extern "C" void kernel_launch(void* const* d_in, const int* in_sizes, int n_in,
                              void* d_out, int out_size, void* d_ws, size_t ws_size,
                              hipStream_t stream) {
    const float* logits = (const float*)d_in[0];   // [B,Q,2048]
    const float* ptime  = (const float*)d_in[1];   // [B,Q,1]
    const int*   labels = (const int*)d_in[2];     // [B,N]
    const float* tstamp = (const float*)d_in[3];   // [B,N,1]
    float* out = (float*)d_out;

    char* ws = (char*)d_ws;
    float* logZ    = (float*)ws;
    float* CgT     = (float*)(ws + 25600);
    float* lsepart = (float*)(ws + 435200);
    float* sums    = (float*)(ws + 438400);
    int*   counter = (int*)(ws + 438408);

    lse_cost_kernel<<<800, 256, 0, stream>>>(logits, ptime, labels, tstamp,
                                             logZ, CgT, lsepart, sums, counter);
    hungarian_kernel<<<BB, 64, 0, stream>>>(CgT, logits, ptime, labels, tstamp,
                                            logZ, lsepart, sums, counter, out);
}